// Round 4
// baseline (770.366 us; speedup 1.0000x reference)
//
#include <hip/hip_runtime.h>
#include <hip/hip_bf16.h>

#define N_TOK 8192
#define DIM   1024
#define HID   4096
#define NEXP  8
#define CSTR  64   // counts stride in ints

using bf16x8 = __attribute__((ext_vector_type(8))) short;
using f32x4  = __attribute__((ext_vector_type(4))) float;

__device__ __forceinline__ void gload_lds16(const void* g, void* l) {
  __builtin_amdgcn_global_load_lds(
      (const __attribute__((address_space(1))) unsigned int*)g,
      (__attribute__((address_space(3))) unsigned int*)l, 16, 0, 0);
}

__device__ __forceinline__ float wredsum(float v) {
#pragma unroll
  for (int off = 32; off > 0; off >>= 1) v += __shfl_xor(v, off, 64);
  return v;
}

__device__ __forceinline__ unsigned short f2bf(float f) {
  __hip_bfloat16 h = __float2bfloat16(f);
  return *reinterpret_cast<unsigned short*>(&h);
}

// ---------------- prep: LN + confidence + router + top-2 dispatch (1 wave / token) ----------------
__global__ __launch_bounds__(256) void prep_kernel(
    const float* __restrict__ x, const float* __restrict__ gamma, const float* __restrict__ beta,
    const float* __restrict__ conf_w, const float* __restrict__ conf_b,
    const float* __restrict__ rw, const float* __restrict__ rb,
    __hip_bfloat16* __restrict__ xn, float* __restrict__ out,
    int* __restrict__ counts, int* __restrict__ lists, float* __restrict__ wts) {
  const int t = blockIdx.x * 4 + (threadIdx.x >> 6);
  const int lane = threadIdx.x & 63;
  const float* xr = x + (size_t)t * DIM;

  float4 xv[4];
#pragma unroll
  for (int q = 0; q < 4; q++) xv[q] = *(const float4*)(xr + q * 256 + lane * 4);

  float s = 0.f, s2 = 0.f;
#pragma unroll
  for (int q = 0; q < 4; q++) {
    s  += xv[q].x + xv[q].y + xv[q].z + xv[q].w;
    s2 += xv[q].x * xv[q].x + xv[q].y * xv[q].y + xv[q].z * xv[q].z + xv[q].w * xv[q].w;
  }
  s = wredsum(s); s2 = wredsum(s2);
  const float mu  = s * (1.f / DIM);
  const float inv = rsqrtf(s2 * (1.f / DIM) - mu * mu + 1e-5f);

  float p[9];
#pragma unroll
  for (int e = 0; e < 9; e++) p[e] = 0.f;

#pragma unroll
  for (int q = 0; q < 4; q++) {
    const int d0 = q * 256 + lane * 4;
    const float4 g4 = *(const float4*)(gamma + d0);
    const float4 b4 = *(const float4*)(beta + d0);
    float v0 = (xv[q].x - mu) * inv * g4.x + b4.x;
    float v1 = (xv[q].y - mu) * inv * g4.y + b4.y;
    float v2 = (xv[q].z - mu) * inv * g4.z + b4.z;
    float v3 = (xv[q].w - mu) * inv * g4.w + b4.w;

    ushort4 st; st.x = f2bf(v0); st.y = f2bf(v1); st.z = f2bf(v2); st.w = f2bf(v3);
    *(ushort4*)((unsigned short*)xn + (size_t)t * DIM + d0) = st;
    *(float4*)(out + (size_t)t * DIM + d0) = xv[q];
    *(float4*)(out + (size_t)N_TOK * DIM + N_TOK + (size_t)t * DIM + d0) = xv[q];

    const float vv[4] = {v0, v1, v2, v3};
#pragma unroll
    for (int j = 0; j < 4; j++) {
      const int d = d0 + j;
      const float v = vv[j];
      p[8] += v * conf_w[d];
      const float4 r0 = *(const float4*)(rw + d * 8);
      const float4 r1 = *(const float4*)(rw + d * 8 + 4);
      p[0] += v * r0.x; p[1] += v * r0.y; p[2] += v * r0.z; p[3] += v * r0.w;
      p[4] += v * r1.x; p[5] += v * r1.y; p[6] += v * r1.z; p[7] += v * r1.w;
    }
  }
#pragma unroll
  for (int e = 0; e < 9; e++) p[e] = wredsum(p[e]);

  if (lane == 0) {
    float L[8];
#pragma unroll
    for (int e = 0; e < 8; e++) L[e] = p[e] + rb[e];
    const float cl = p[8] + conf_b[0];
    out[(size_t)N_TOK * DIM + t] = 1.f / (1.f + expf(-cl));

    float mx = L[0];
#pragma unroll
    for (int e = 1; e < 8; e++) mx = fmaxf(mx, L[e]);
    float pe[8];
#pragma unroll
    for (int e = 0; e < 8; e++) pe[e] = expf(L[e] - mx);
    int i0 = 0; float v0 = pe[0];
#pragma unroll
    for (int e = 1; e < 8; e++) if (pe[e] > v0) { v0 = pe[e]; i0 = e; }
    int i1 = -1; float v1 = -1.f;
#pragma unroll
    for (int e = 0; e < 8; e++) if (e != i0 && pe[e] > v1) { v1 = pe[e]; i1 = e; }
    const float wsum = v0 + v1;
    const float w0 = v0 / wsum, w1 = v1 / wsum;
    int p0 = atomicAdd(&counts[i0 * CSTR], 1);
    lists[i0 * N_TOK + p0] = t; wts[i0 * N_TOK + p0] = w0;
    int p1 = atomicAdd(&counts[i1 * CSTR], 1);
    lists[i1 * N_TOK + p1] = t; wts[i1 * N_TOK + p1] = w1;
  }
}

// ---------------- exclusive prefix sum of counts -> bases ----------------
__global__ void bases_kernel(const int* __restrict__ counts, int* __restrict__ bases) {
  if (threadIdx.x == 0) {
    int s = 0;
#pragma unroll
    for (int e = 0; e < NEXP; e++) { bases[e] = s; s += counts[e * CSTR]; }
  }
}

// ---------------- transpose + cast fp32[R][C] -> bf16[C][R], 64x64 tiles, z = matrix ----------------
__global__ __launch_bounds__(256) void transpose_cast64(
    const float* __restrict__ src0, __hip_bfloat16* __restrict__ dst0, int R, int C) {
  __shared__ float tile[64][65];
  const size_t msz = (size_t)R * C;
  const float* src = src0 + blockIdx.z * msz;
  __hip_bfloat16* dst = dst0 + blockIdx.z * msz;
  const int c0 = blockIdx.x * 64, r0 = blockIdx.y * 64;
  const int tid = threadIdx.x;
  const int tx = tid & 15, ty = tid >> 4;
#pragma unroll
  for (int k = 0; k < 4; k++) {
    const int row = ty + k * 16;
    const float4 v = *(const float4*)(src + (size_t)(r0 + row) * C + c0 + tx * 4);
    tile[row][tx * 4 + 0] = v.x; tile[row][tx * 4 + 1] = v.y;
    tile[row][tx * 4 + 2] = v.z; tile[row][tx * 4 + 3] = v.w;
  }
  __syncthreads();
#pragma unroll
  for (int k = 0; k < 4; k++) {
    const int orow = ty + k * 16;
    ushort4 st;
    st.x = f2bf(tile[tx * 4 + 0][orow]);
    st.y = f2bf(tile[tx * 4 + 1][orow]);
    st.z = f2bf(tile[tx * 4 + 2][orow]);
    st.w = f2bf(tile[tx * 4 + 3][orow]);
    *(ushort4*)((unsigned short*)dst + (size_t)(c0 + orow) * R + r0 + tx * 4) = st;
  }
}

// ============ 256x256 / BK=32 / 4-slot distance-3 pipelined GEMMs ============
// Slot s (32 KB): A [256 rows][64 B] at s*32768, B at +16384. Row r, 16B chunk c
// stored at phys chunk c ^ ((r>>1)&3) (2-way banks = free). gload_lds dest is
// linear (uniform + l*16); the swizzle is applied to the SOURCE address and the
// same involution on ds_read (rule 21).

// ---------------- GEMM1: hbuf[base+pos] = relu(gather(xn) @ w1t^T + b1) ----------------
__global__ __launch_bounds__(512) void gemm1_kernel(
    const __hip_bfloat16* __restrict__ xn, const __hip_bfloat16* __restrict__ w1t_b,
    const float* __restrict__ b1, const int* __restrict__ lists,
    const int* __restrict__ counts, const int* __restrict__ bases,
    __hip_bfloat16* __restrict__ hbuf, const int e0) {
  const int e = e0 + (int)(blockIdx.y >> 5);
  const int rt = blockIdx.y & 31;
  const int cnt = counts[e * CSTR];
  if (rt * 256 >= cnt) return;
  const int hbase = bases[e];
  const int ct = blockIdx.x;
  const int* list = lists + e * N_TOK;
  const __hip_bfloat16* w1t = w1t_b + (size_t)(e - e0) * DIM * HID;

  __shared__ char smem[131072];
  const int tid = threadIdx.x;
  const int l = tid & 63;
  const int w = tid >> 6;
  const int wr = w >> 2;
  const int wc = w & 3;

  // staging: 2 A-rows + 2 B-rows per thread per tile (4 loads); phys chunk = l&3
  const int logc8 = ((l & 3) ^ ((l >> 3) & 3)) * 8;  // source logical chunk (elems)
  const unsigned short* srcA[2];
  const unsigned short* srcB[2];
  int ldsoff[2];
#pragma unroll
  for (int j = 0; j < 2; j++) {
    const int row = w * 32 + j * 16 + (l >> 2);
    const int pos = rt * 256 + row;
    const int tok = list[pos < cnt ? pos : 0];
    srcA[j] = (const unsigned short*)xn + (size_t)tok * DIM + logc8;
    srcB[j] = (const unsigned short*)w1t + (size_t)(ct * 256 + row) * DIM + logc8;
    ldsoff[j] = w * 2048 + j * 1024 + l * 16;
  }
  auto stage = [&](int t, int slot) {
#pragma unroll
    for (int j = 0; j < 2; j++)
      gload_lds16(srcA[j] + t * 32, smem + slot * 32768 + ldsoff[j]);
#pragma unroll
    for (int j = 0; j < 2; j++)
      gload_lds16(srcB[j] + t * 32, smem + slot * 32768 + 16384 + ldsoff[j]);
  };

  // fragment addressing
  const int lr = l & 15;
  const int physb = (((l >> 4) ^ ((lr >> 1) & 3)) << 4);
  const int rowAb = (wr * 128 + lr) * 64 + physb;
  const int rowBb = 16384 + (wc * 64 + lr) * 64 + physb;

  f32x4 acc[8][4] = {};
  stage(0, 0); stage(1, 1); stage(2, 2);
  const int nk = DIM / 32;
  for (int t = 0; t < nk; ++t) {
    const int slot = t & 3;
    __builtin_amdgcn_sched_barrier(0);
    __builtin_amdgcn_s_barrier();             // all waves done reading slot (t+3)&3
    if (t + 3 < nk) {
      stage(t + 3, (t + 3) & 3);
      asm volatile("s_waitcnt vmcnt(12)" ::: "memory");
    } else if (t + 3 == nk) {
      asm volatile("s_waitcnt vmcnt(8)" ::: "memory");
    } else if (t + 2 == nk) {
      asm volatile("s_waitcnt vmcnt(4)" ::: "memory");
    } else {
      asm volatile("s_waitcnt vmcnt(0)" ::: "memory");
    }
    __builtin_amdgcn_s_barrier();             // tile t landed (all waves)
    __builtin_amdgcn_sched_barrier(0);

    const char* Ab = smem + slot * 32768 + rowAb;
    const char* Bb = smem + slot * 32768 + rowBb;
    bf16x8 bfr[4], afr[8];
#pragma unroll
    for (int n = 0; n < 4; n++) bfr[n] = *(const bf16x8*)(Bb + n * 1024);
#pragma unroll
    for (int m = 0; m < 8; m++) afr[m] = *(const bf16x8*)(Ab + m * 1024);
    __builtin_amdgcn_s_setprio(1);
#pragma unroll
    for (int m = 0; m < 8; m++)
#pragma unroll
      for (int n = 0; n < 4; n++)
        acc[m][n] = __builtin_amdgcn_mfma_f32_16x16x32_bf16(afr[m], bfr[n], acc[m][n], 0, 0, 0);
    __builtin_amdgcn_s_setprio(0);
  }

#pragma unroll
  for (int n = 0; n < 4; n++) {
    const int col = ct * 256 + wc * 64 + n * 16 + lr;
    const float bv = b1[e * HID + col];
#pragma unroll
    for (int m = 0; m < 8; m++) {
      f32x4 v = acc[m][n];
#pragma unroll
      for (int j = 0; j < 4; j++) {
        const int pos = rt * 256 + wr * 128 + m * 16 + (l >> 4) * 4 + j;
        if (pos < cnt)
          hbuf[(size_t)(hbase + pos) * HID + col] = __float2bfloat16(fmaxf(v[j] + bv, 0.f));
      }
    }
  }
}

// ---------------- GEMM2 (split-K x2): out[tok] += w * (hbuf @ w2t^T + b2) ----------------
__global__ __launch_bounds__(512) void gemm2_kernel(
    const __hip_bfloat16* __restrict__ hbuf, const __hip_bfloat16* __restrict__ w2t_b,
    const float* __restrict__ b2, const int* __restrict__ lists,
    const float* __restrict__ wts, const int* __restrict__ counts,
    const int* __restrict__ bases, float* __restrict__ out, const int e0) {
  const int e = e0 + (int)(blockIdx.y >> 6);
  const int rt = (int)((blockIdx.y >> 1) & 31);
  const int ksp = (int)(blockIdx.y & 1);
  const int cnt = counts[e * CSTR];
  if (rt * 256 >= cnt) return;
  const int hbase = bases[e];
  const int ct = blockIdx.x;
  const __hip_bfloat16* w2t = w2t_b + (size_t)(e - e0) * DIM * HID;
  const int kbase = ksp * (HID / 2);

  __shared__ char smem[131072];
  __shared__ int s_tok[256];
  __shared__ float s_w[256];
  const int tid = threadIdx.x;
  const int l = tid & 63;
  const int w = tid >> 6;
  const int wr = w >> 2;
  const int wc = w & 3;

  if (tid < 256) {
    const int pos = rt * 256 + tid;
    const bool vld = pos < cnt;
    s_tok[tid] = vld ? lists[e * N_TOK + pos] : -1;
    s_w[tid]  = vld ? wts[e * N_TOK + pos] : 0.f;
  }
  __syncthreads();   // also drains the s_tok/s_w loads from vmcnt

  const int logc8 = ((l & 3) ^ ((l >> 3) & 3)) * 8;
  const unsigned short* srcA[2];
  const unsigned short* srcB[2];
  int ldsoff[2];
#pragma unroll
  for (int j = 0; j < 2; j++) {
    const int row = w * 32 + j * 16 + (l >> 2);
    srcA[j] = (const unsigned short*)hbuf + (size_t)(hbase + rt * 256 + row) * HID + kbase + logc8;
    srcB[j] = (const unsigned short*)w2t + (size_t)(ct * 256 + row) * HID + kbase + logc8;
    ldsoff[j] = w * 2048 + j * 1024 + l * 16;
  }
  auto stage = [&](int t, int slot) {
#pragma unroll
    for (int j = 0; j < 2; j++)
      gload_lds16(srcA[j] + t * 32, smem + slot * 32768 + ldsoff[j]);
#pragma unroll
    for (int j = 0; j < 2; j++)
      gload_lds16(srcB[j] + t * 32, smem + slot * 32768 + 16384 + ldsoff[j]);
  };

  const int lr = l & 15;
  const int physb = (((l >> 4) ^ ((lr >> 1) & 3)) << 4);
  const int rowAb = (wr * 128 + lr) * 64 + physb;
  const int rowBb = 16384 + (wc * 64 + lr) * 64 + physb;

  f32x4 acc[8][4] = {};
  stage(0, 0); stage(1, 1); stage(2, 2);
  const int nk = (HID / 2) / 32;
  for (int t = 0; t < nk; ++t) {
    const int slot = t & 3;
    __builtin_amdgcn_sched_barrier(0);
    __builtin_amdgcn_s_barrier();
    if (t + 3 < nk) {
      stage(t + 3, (t + 3) & 3);
      asm volatile("s_waitcnt vmcnt(12)" ::: "memory");
    } else if (t + 3 == nk) {
      asm volatile("s_waitcnt vmcnt(8)" ::: "memory");
    } else if (t + 2 == nk) {
      asm volatile("s_waitcnt vmcnt(4)" ::: "memory");
    } else {
      asm volatile("s_waitcnt vmcnt(0)" ::: "memory");
    }
    __builtin_amdgcn_s_barrier();
    __builtin_amdgcn_sched_barrier(0);

    const char* Ab = smem + slot * 32768 + rowAb;
    const char* Bb = smem + slot * 32768 + rowBb;
    bf16x8 bfr[4], afr[8];
#pragma unroll
    for (int n = 0; n < 4; n++) bfr[n] = *(const bf16x8*)(Bb + n * 1024);
#pragma unroll
    for (int m = 0; m < 8; m++) afr[m] = *(const bf16x8*)(Ab + m * 1024);
    __builtin_amdgcn_s_setprio(1);
#pragma unroll
    for (int m = 0; m < 8; m++)
#pragma unroll
      for (int n = 0; n < 4; n++)
        acc[m][n] = __builtin_amdgcn_mfma_f32_16x16x32_bf16(afr[m], bfr[n], acc[m][n], 0, 0, 0);
    __builtin_amdgcn_s_setprio(0);
  }

#pragma unroll
  for (int n = 0; n < 4; n++) {
    const int col = ct * 256 + wc * 64 + n * 16 + lr;
    const float bv = (ksp == 0) ? b2[e * DIM + col] : 0.f;
#pragma unroll
    for (int m = 0; m < 8; m++) {
      f32x4 v = acc[m][n];
#pragma unroll
      for (int j = 0; j < 4; j++) {
        const int rowi = wr * 128 + m * 16 + (l >> 4) * 4 + j;
        const int tok = s_tok[rowi];
        if (tok >= 0)
          unsafeAtomicAdd(out + (size_t)tok * DIM + col, s_w[rowi] * (v[j] + bv));
      }
    }
  }
}

extern "C" void kernel_launch(void* const* d_in, const int* in_sizes, int n_in,
                              void* d_out, int out_size, void* d_ws, size_t ws_size,
                              hipStream_t stream) {
  (void)in_sizes; (void)n_in; (void)out_size;
  const float* x      = (const float*)d_in[0];
  const float* gamma  = (const float*)d_in[1];
  const float* beta   = (const float*)d_in[2];
  const float* conf_w = (const float*)d_in[3];
  const float* conf_b = (const float*)d_in[4];
  const float* rw     = (const float*)d_in[5];
  const float* rb     = (const float*)d_in[6];
  const float* w1     = (const float*)d_in[7];
  const float* b1     = (const float*)d_in[8];
  const float* w2     = (const float*)d_in[9];
  const float* b2     = (const float*)d_in[10];
  float* out = (float*)d_out;

  char* w = (char*)d_ws;
  auto alloc = [&](size_t bytes) { char* p = w; w += (bytes + 255) & ~255ULL; return p; };

  __hip_bfloat16* xn = (__hip_bfloat16*)alloc((size_t)N_TOK * DIM * 2);
  int*   lists  = (int*)alloc((size_t)NEXP * N_TOK * 4);
  float* wtsb   = (float*)alloc((size_t)NEXP * N_TOK * 4);
  int*   counts = (int*)alloc(NEXP * CSTR * 4);
  int*   bases  = (int*)alloc(256);
  size_t common = (size_t)(w - (char*)d_ws);

  const size_t hbufA = (size_t)(2 * N_TOK + 512) * HID * 2;
  const size_t wtA   = (size_t)NEXP * DIM * HID * 2;
  const bool planA = ws_size >= common + hbufA + 2 * wtA + 4096;

  hipMemsetAsync(counts, 0, NEXP * CSTR * 4, stream);
  prep_kernel<<<N_TOK / 4, 256, 0, stream>>>(x, gamma, beta, conf_w, conf_b, rw, rb,
                                             xn, out, counts, lists, wtsb);

  if (planA) {
    __hip_bfloat16* hbuf = (__hip_bfloat16*)alloc(hbufA);
    __hip_bfloat16* w1t  = (__hip_bfloat16*)alloc(wtA);
    __hip_bfloat16* w2t  = (__hip_bfloat16*)alloc(wtA);
    bases_kernel<<<1, 64, 0, stream>>>(counts, bases);
    transpose_cast64<<<dim3(HID / 64, DIM / 64, NEXP), 256, 0, stream>>>(w1, w1t, DIM, HID);
    transpose_cast64<<<dim3(DIM / 64, HID / 64, NEXP), 256, 0, stream>>>(w2, w2t, HID, DIM);
    gemm1_kernel<<<dim3(HID / 256, NEXP * 32), 512, 0, stream>>>(
        xn, w1t, b1, lists, counts, bases, hbuf, 0);
    gemm2_kernel<<<dim3(DIM / 256, NEXP * 64), 512, 0, stream>>>(
        hbuf, w2t, b2, lists, wtsb, counts, bases, out, 0);
  } else {
    __hip_bfloat16* hbuf = (__hip_bfloat16*)alloc((size_t)(N_TOK + 512) * HID * 2);
    __hip_bfloat16* wt   = (__hip_bfloat16*)alloc((size_t)DIM * HID * 2);
    hipMemsetAsync(bases, 0, 256, stream);
    for (int e = 0; e < NEXP; e++) {
      transpose_cast64<<<dim3(HID / 64, DIM / 64, 1), 256, 0, stream>>>(
          w1 + (size_t)e * DIM * HID, wt, DIM, HID);
      gemm1_kernel<<<dim3(HID / 256, 32), 512, 0, stream>>>(
          xn, wt, b1, lists, counts, bases, hbuf, e);
      transpose_cast64<<<dim3(DIM / 64, HID / 64, 1), 256, 0, stream>>>(
          w2 + (size_t)e * HID * DIM, wt, HID, DIM);
      gemm2_kernel<<<dim3(DIM / 256, 64), 512, 0, stream>>>(
          hbuf, wt, b2, lists, wtsb, counts, bases, out, e);
    }
  }
}

// Round 5
// 621.892 us; speedup vs baseline: 1.2387x; 1.2387x over previous
//
#include <hip/hip_runtime.h>
#include <hip/hip_bf16.h>

#define N_TOK 8192
#define DIM   1024
#define HID   4096
#define NEXP  8
#define CSTR  64   // counts stride in ints

using bf16x8 = __attribute__((ext_vector_type(8))) short;
using f32x4  = __attribute__((ext_vector_type(4))) float;

__device__ __forceinline__ void gload_lds16(const void* g, void* l) {
  __builtin_amdgcn_global_load_lds(
      (const __attribute__((address_space(1))) unsigned int*)g,
      (__attribute__((address_space(3))) unsigned int*)l, 16, 0, 0);
}

__device__ __forceinline__ float wredsum(float v) {
#pragma unroll
  for (int off = 32; off > 0; off >>= 1) v += __shfl_xor(v, off, 64);
  return v;
}

__device__ __forceinline__ unsigned short f2bf(float f) {
  __hip_bfloat16 h = __float2bfloat16(f);
  return *reinterpret_cast<unsigned short*>(&h);
}
__device__ __forceinline__ float bf2f(unsigned short u) {
  return __uint_as_float((unsigned)u << 16);
}

// ---------------- prep: LN + confidence + router + top-2 dispatch (1 wave / token) ----------------
__global__ __launch_bounds__(256) void prep_kernel(
    const float* __restrict__ x, const float* __restrict__ gamma, const float* __restrict__ beta,
    const float* __restrict__ conf_w, const float* __restrict__ conf_b,
    const float* __restrict__ rw, const float* __restrict__ rb,
    __hip_bfloat16* __restrict__ xn, float* __restrict__ out,
    int* __restrict__ counts, int* __restrict__ lists, float* __restrict__ wts,
    int2* __restrict__ idx) {
  const int t = blockIdx.x * 4 + (threadIdx.x >> 6);
  const int lane = threadIdx.x & 63;
  const float* xr = x + (size_t)t * DIM;

  float4 xv[4];
#pragma unroll
  for (int q = 0; q < 4; q++) xv[q] = *(const float4*)(xr + q * 256 + lane * 4);

  float s = 0.f, s2 = 0.f;
#pragma unroll
  for (int q = 0; q < 4; q++) {
    s  += xv[q].x + xv[q].y + xv[q].z + xv[q].w;
    s2 += xv[q].x * xv[q].x + xv[q].y * xv[q].y + xv[q].z * xv[q].z + xv[q].w * xv[q].w;
  }
  s = wredsum(s); s2 = wredsum(s2);
  const float mu  = s * (1.f / DIM);
  const float inv = rsqrtf(s2 * (1.f / DIM) - mu * mu + 1e-5f);

  float p[9];
#pragma unroll
  for (int e = 0; e < 9; e++) p[e] = 0.f;

#pragma unroll
  for (int q = 0; q < 4; q++) {
    const int d0 = q * 256 + lane * 4;
    const float4 g4 = *(const float4*)(gamma + d0);
    const float4 b4 = *(const float4*)(beta + d0);
    float v0 = (xv[q].x - mu) * inv * g4.x + b4.x;
    float v1 = (xv[q].y - mu) * inv * g4.y + b4.y;
    float v2 = (xv[q].z - mu) * inv * g4.z + b4.z;
    float v3 = (xv[q].w - mu) * inv * g4.w + b4.w;

    ushort4 st; st.x = f2bf(v0); st.y = f2bf(v1); st.z = f2bf(v2); st.w = f2bf(v3);
    *(ushort4*)((unsigned short*)xn + (size_t)t * DIM + d0) = st;
    *(float4*)(out + (size_t)t * DIM + d0) = xv[q];
    *(float4*)(out + (size_t)N_TOK * DIM + N_TOK + (size_t)t * DIM + d0) = xv[q];

    const float vv[4] = {v0, v1, v2, v3};
#pragma unroll
    for (int j = 0; j < 4; j++) {
      const int d = d0 + j;
      const float v = vv[j];
      p[8] += v * conf_w[d];
      const float4 r0 = *(const float4*)(rw + d * 8);
      const float4 r1 = *(const float4*)(rw + d * 8 + 4);
      p[0] += v * r0.x; p[1] += v * r0.y; p[2] += v * r0.z; p[3] += v * r0.w;
      p[4] += v * r1.x; p[5] += v * r1.y; p[6] += v * r1.z; p[7] += v * r1.w;
    }
  }
#pragma unroll
  for (int e = 0; e < 9; e++) p[e] = wredsum(p[e]);

  if (lane == 0) {
    float L[8];
#pragma unroll
    for (int e = 0; e < 8; e++) L[e] = p[e] + rb[e];
    const float cl = p[8] + conf_b[0];
    out[(size_t)N_TOK * DIM + t] = 1.f / (1.f + expf(-cl));

    float mx = L[0];
#pragma unroll
    for (int e = 1; e < 8; e++) mx = fmaxf(mx, L[e]);
    float pe[8];
#pragma unroll
    for (int e = 0; e < 8; e++) pe[e] = expf(L[e] - mx);
    int i0 = 0; float v0 = pe[0];
#pragma unroll
    for (int e = 1; e < 8; e++) if (pe[e] > v0) { v0 = pe[e]; i0 = e; }
    int i1 = -1; float v1 = -1.f;
#pragma unroll
    for (int e = 0; e < 8; e++) if (e != i0 && pe[e] > v1) { v1 = pe[e]; i1 = e; }
    const float wsum = v0 + v1;
    const float w0 = v0 / wsum, w1 = v1 / wsum;
    int p0 = atomicAdd(&counts[i0 * CSTR], 1);
    lists[i0 * N_TOK + p0] = t; wts[i0 * N_TOK + p0] = w0;
    int p1 = atomicAdd(&counts[i1 * CSTR], 1);
    lists[i1 * N_TOK + p1] = t; wts[i1 * N_TOK + p1] = w1;
    idx[t] = make_int2((i0 << 13) | p0, (i1 << 13) | p1);
  }
}

// ---------------- exclusive prefix sum of counts -> bases ----------------
__global__ void bases_kernel(const int* __restrict__ counts, int* __restrict__ bases) {
  if (threadIdx.x == 0) {
    int s = 0;
#pragma unroll
    for (int e = 0; e < NEXP; e++) { bases[e] = s; s += counts[e * CSTR]; }
  }
}

// ---------------- transpose + cast fp32[R][C] -> bf16[C][R], 64x64 tiles, z = matrix ----------------
__global__ __launch_bounds__(256) void transpose_cast64(
    const float* __restrict__ src0, __hip_bfloat16* __restrict__ dst0, int R, int C) {
  __shared__ float tile[64][65];
  const size_t msz = (size_t)R * C;
  const float* src = src0 + blockIdx.z * msz;
  __hip_bfloat16* dst = dst0 + blockIdx.z * msz;
  const int c0 = blockIdx.x * 64, r0 = blockIdx.y * 64;
  const int tid = threadIdx.x;
  const int tx = tid & 15, ty = tid >> 4;
#pragma unroll
  for (int k = 0; k < 4; k++) {
    const int row = ty + k * 16;
    const float4 v = *(const float4*)(src + (size_t)(r0 + row) * C + c0 + tx * 4);
    tile[row][tx * 4 + 0] = v.x; tile[row][tx * 4 + 1] = v.y;
    tile[row][tx * 4 + 2] = v.z; tile[row][tx * 4 + 3] = v.w;
  }
  __syncthreads();
#pragma unroll
  for (int k = 0; k < 4; k++) {
    const int orow = ty + k * 16;
    ushort4 st;
    st.x = f2bf(tile[tx * 4 + 0][orow]);
    st.y = f2bf(tile[tx * 4 + 1][orow]);
    st.z = f2bf(tile[tx * 4 + 2][orow]);
    st.w = f2bf(tile[tx * 4 + 3][orow]);
    *(ushort4*)((unsigned short*)dst + (size_t)(c0 + orow) * R + r0 + tx * 4) = st;
  }
}

// ============ 256x256 / BK=64 / 8-phase (4 phases per K-tile) GEMMs ============
// Buffer p (64 KB) at p*65536: A [256 rows][128 B] at +0, B at +32768.
// 16B chunk c of row r stored at phys chunk c ^ (r&7); gload_lds dest linear,
// swizzle applied to SOURCE address and identically on ds_read (rule 21).
// Phase q of tile t: {ds_read quadrant q frags | stage pair q of tile t+1 into
// buf p^1 (vacated at end of tile t-1); barrier; lgkmcnt(0); 16 MFMA; barrier}.
// vmcnt(2) at phase 0 only: exactly the 2 loads of tile t+1's pair-0 may be
// outstanding; in-order vmcnt retire => tile t's 8 loads landed; barrier makes
// it collective across waves.

#define GEMM_CORE(NT)                                                                   \
  f32x4 acc[8][4] = {};                                                                 \
  stage_pair(0, 0); stage_pair(0, 1); stage_pair(0, 2); stage_pair(0, 3);               \
  for (int t = 0; t < (NT); ++t) {                                                      \
    const int p = t & 1;                                                                \
    const char* Ab = smem + p * 65536 + rowAb;                                          \
    const char* Bb = smem + p * 65536 + rowBb;                                          \
    const bool st = (t + 1 < (NT));                                                     \
    bf16x8 bfr[4][2];                                                                   \
    if (st) { stage_pair(t + 1, 0); asm volatile("s_waitcnt vmcnt(2)" ::: "memory"); }  \
    else    { asm volatile("s_waitcnt vmcnt(0)" ::: "memory"); }                        \
    __builtin_amdgcn_s_barrier();                                                       \
    {                                                                                   \
      _Pragma("unroll")                                                                 \
      for (int n = 0; n < 4; n++) {                                                     \
        bfr[n][0] = *(const bf16x8*)(Bb + n * 2048 + c0);                               \
        bfr[n][1] = *(const bf16x8*)(Bb + n * 2048 + c1);                               \
      }                                                                                 \
      bf16x8 af[2][2];                                                                  \
      _Pragma("unroll")                                                                 \
      for (int mm = 0; mm < 2; mm++) {                                                  \
        af[mm][0] = *(const bf16x8*)(Ab + mm * 2048 + c0);                              \
        af[mm][1] = *(const bf16x8*)(Ab + mm * 2048 + c1);                              \
      }                                                                                 \
      asm volatile("s_waitcnt lgkmcnt(0)" ::: "memory");                                \
      __builtin_amdgcn_sched_barrier(0);                                                \
      __builtin_amdgcn_s_setprio(1);                                                    \
      _Pragma("unroll")                                                                 \
      for (int mm = 0; mm < 2; mm++)                                                    \
        _Pragma("unroll")                                                               \
        for (int n = 0; n < 4; n++) {                                                   \
          acc[mm][n] = __builtin_amdgcn_mfma_f32_16x16x32_bf16(af[mm][0], bfr[n][0], acc[mm][n], 0, 0, 0); \
          acc[mm][n] = __builtin_amdgcn_mfma_f32_16x16x32_bf16(af[mm][1], bfr[n][1], acc[mm][n], 0, 0, 0); \
        }                                                                               \
      __builtin_amdgcn_s_setprio(0);                                                    \
    }                                                                                   \
    __builtin_amdgcn_s_barrier();                                                       \
    _Pragma("unroll")                                                                   \
    for (int q = 1; q < 4; q++) {                                                       \
      bf16x8 af[2][2];                                                                  \
      _Pragma("unroll")                                                                 \
      for (int mm = 0; mm < 2; mm++) {                                                  \
        af[mm][0] = *(const bf16x8*)(Ab + (q * 2 + mm) * 2048 + c0);                    \
        af[mm][1] = *(const bf16x8*)(Ab + (q * 2 + mm) * 2048 + c1);                    \
      }                                                                                 \
      if (st) stage_pair(t + 1, q);                                                     \
      __builtin_amdgcn_s_barrier();                                                     \
      asm volatile("s_waitcnt lgkmcnt(0)" ::: "memory");                                \
      __builtin_amdgcn_sched_barrier(0);                                                \
      __builtin_amdgcn_s_setprio(1);                                                    \
      _Pragma("unroll")                                                                 \
      for (int mm = 0; mm < 2; mm++)                                                    \
        _Pragma("unroll")                                                               \
        for (int n = 0; n < 4; n++) {                                                   \
          acc[q * 2 + mm][n] = __builtin_amdgcn_mfma_f32_16x16x32_bf16(af[mm][0], bfr[n][0], acc[q * 2 + mm][n], 0, 0, 0); \
          acc[q * 2 + mm][n] = __builtin_amdgcn_mfma_f32_16x16x32_bf16(af[mm][1], bfr[n][1], acc[q * 2 + mm][n], 0, 0, 0); \
        }                                                                               \
      __builtin_amdgcn_s_setprio(0);                                                    \
      __builtin_amdgcn_s_barrier();                                                     \
    }                                                                                   \
  }

// ---------------- GEMM1: hbuf[base+pos] = relu(gather(xn) @ w1t^T + b1) ----------------
__global__ __launch_bounds__(512) void gemm1_kernel(
    const __hip_bfloat16* __restrict__ xn, const __hip_bfloat16* __restrict__ w1t_b,
    const float* __restrict__ b1, const int* __restrict__ lists,
    const int* __restrict__ counts, const int* __restrict__ bases,
    __hip_bfloat16* __restrict__ hbuf, const int e0) {
  const int e = e0 + (int)(blockIdx.y >> 5);
  const int rt = blockIdx.y & 31;
  const int cnt = counts[e * CSTR];
  if (rt * 256 >= cnt) return;
  const int hbase = bases[e];
  const int ct = blockIdx.x;
  const int* list = lists + e * N_TOK;
  const __hip_bfloat16* w1t = w1t_b + (size_t)(e - e0) * DIM * HID;

  __shared__ char smem[131072];
  const int tid = threadIdx.x;
  const int l = tid & 63;
  const int w = tid >> 6;
  const int wr = w >> 2;
  const int wc = w & 3;

  const int schunk = ((l & 7) ^ ((l >> 3) & 7)) * 8;  // pre-swizzled source col (elems)
  const unsigned short* srcA[4];
  const unsigned short* srcB[4];
  int ldsoff[4];
#pragma unroll
  for (int j = 0; j < 4; j++) {
    const int row = w * 32 + j * 8 + (l >> 3);
    const int pos = rt * 256 + row;
    const int tok = list[pos < cnt ? pos : 0];
    srcA[j] = (const unsigned short*)xn + (size_t)tok * DIM + schunk;
    srcB[j] = (const unsigned short*)w1t + (size_t)(ct * 256 + row) * DIM + schunk;
    ldsoff[j] = w * 4096 + j * 1024 + l * 16;
  }
  auto stage_pair = [&](int tt, int j) {
    const int pp = tt & 1;
    gload_lds16(srcA[j] + tt * 64, smem + pp * 65536 + ldsoff[j]);
    gload_lds16(srcB[j] + tt * 64, smem + pp * 65536 + 32768 + ldsoff[j]);
  };

  const int lr = l & 15;
  const int c0 = (((l >> 4) + 0) ^ (l & 7)) << 4;
  const int c1 = (((l >> 4) + 4) ^ (l & 7)) << 4;
  const int rowAb = (wr * 128 + lr) * 128;
  const int rowBb = 32768 + (wc * 64 + lr) * 128;

  GEMM_CORE(DIM / 64)

#pragma unroll
  for (int n = 0; n < 4; n++) {
    const int col = ct * 256 + wc * 64 + n * 16 + lr;
    const float bv = b1[e * HID + col];
#pragma unroll
    for (int m = 0; m < 8; m++) {
      f32x4 v = acc[m][n];
#pragma unroll
      for (int j = 0; j < 4; j++) {
        const int pos = rt * 256 + wr * 128 + m * 16 + (l >> 4) * 4 + j;
        if (pos < cnt)
          hbuf[(size_t)(hbase + pos) * HID + col] = __float2bfloat16(fmaxf(v[j] + bv, 0.f));
      }
    }
  }
}

// ---------------- GEMM2: ybuf[base+pos] = hbuf @ w2t^T  (pure stores, no atomics) ----------------
__global__ __launch_bounds__(512) void gemm2_kernel(
    const __hip_bfloat16* __restrict__ hbuf, const __hip_bfloat16* __restrict__ w2t_b,
    const int* __restrict__ counts, const int* __restrict__ bases,
    __hip_bfloat16* __restrict__ ybuf, const int e0) {
  const int e = e0 + (int)(blockIdx.y >> 5);
  const int rt = blockIdx.y & 31;
  const int cnt = counts[e * CSTR];
  if (rt * 256 >= cnt) return;
  const int hbase = bases[e];
  const int ct = blockIdx.x;
  const __hip_bfloat16* w2t = w2t_b + (size_t)(e - e0) * DIM * HID;

  __shared__ char smem[131072];
  const int tid = threadIdx.x;
  const int l = tid & 63;
  const int w = tid >> 6;
  const int wr = w >> 2;
  const int wc = w & 3;

  const int schunk = ((l & 7) ^ ((l >> 3) & 7)) * 8;
  const unsigned short* srcA[4];
  const unsigned short* srcB[4];
  int ldsoff[4];
#pragma unroll
  for (int j = 0; j < 4; j++) {
    const int row = w * 32 + j * 8 + (l >> 3);
    srcA[j] = (const unsigned short*)hbuf + (size_t)(hbase + rt * 256 + row) * HID + schunk;
    srcB[j] = (const unsigned short*)w2t + (size_t)(ct * 256 + row) * HID + schunk;
    ldsoff[j] = w * 4096 + j * 1024 + l * 16;
  }
  auto stage_pair = [&](int tt, int j) {
    const int pp = tt & 1;
    gload_lds16(srcA[j] + tt * 64, smem + pp * 65536 + ldsoff[j]);
    gload_lds16(srcB[j] + tt * 64, smem + pp * 65536 + 32768 + ldsoff[j]);
  };

  const int lr = l & 15;
  const int c0 = (((l >> 4) + 0) ^ (l & 7)) << 4;
  const int c1 = (((l >> 4) + 4) ^ (l & 7)) << 4;
  const int rowAb = (wr * 128 + lr) * 128;
  const int rowBb = 32768 + (wc * 64 + lr) * 128;

  GEMM_CORE(HID / 64)

#pragma unroll
  for (int n = 0; n < 4; n++) {
    const int col = ct * 256 + wc * 64 + n * 16 + lr;
#pragma unroll
    for (int m = 0; m < 8; m++) {
      f32x4 v = acc[m][n];
#pragma unroll
      for (int j = 0; j < 4; j++) {
        const int pos = rt * 256 + wr * 128 + m * 16 + (l >> 4) * 4 + j;
        if (pos < cnt)
          ybuf[(size_t)(hbase + pos) * DIM + col] = __float2bfloat16(v[j]);
      }
    }
  }
}

// ---------------- combine: out[t] += w0*(y0+b2[e0]) + w1*(y1+b2[e1]) ----------------
__global__ __launch_bounds__(256) void combine_kernel(
    const __hip_bfloat16* __restrict__ ybuf, const float* __restrict__ b2,
    const int2* __restrict__ idx, const float* __restrict__ wv,
    const int* __restrict__ bases, float* __restrict__ out) {
  const int t = blockIdx.x * 4 + (threadIdx.x >> 6);
  const int lane = threadIdx.x & 63;
  const int2 iv = idx[t];
  const int e0 = iv.x >> 13, p0 = iv.x & (N_TOK - 1);
  const int e1 = iv.y >> 13, p1 = iv.y & (N_TOK - 1);
  const float w0 = wv[iv.x], w1 = wv[iv.y];
  const size_t r0 = (size_t)(bases[e0] + p0) * DIM;
  const size_t r1 = (size_t)(bases[e1] + p1) * DIM;
#pragma unroll
  for (int q = 0; q < 4; q++) {
    const int d0 = q * 256 + lane * 4;
    float4 o = *(const float4*)(out + (size_t)t * DIM + d0);
    const ushort4 y0 = *(const ushort4*)((const unsigned short*)ybuf + r0 + d0);
    const ushort4 y1 = *(const ushort4*)((const unsigned short*)ybuf + r1 + d0);
    const float4 bb0 = *(const float4*)(b2 + e0 * DIM + d0);
    const float4 bb1 = *(const float4*)(b2 + e1 * DIM + d0);
    o.x += w0 * (bf2f(y0.x) + bb0.x) + w1 * (bf2f(y1.x) + bb1.x);
    o.y += w0 * (bf2f(y0.y) + bb0.y) + w1 * (bf2f(y1.y) + bb1.y);
    o.z += w0 * (bf2f(y0.z) + bb0.z) + w1 * (bf2f(y1.z) + bb1.z);
    o.w += w0 * (bf2f(y0.w) + bb0.w) + w1 * (bf2f(y1.w) + bb1.w);
    *(float4*)(out + (size_t)t * DIM + d0) = o;
  }
}

extern "C" void kernel_launch(void* const* d_in, const int* in_sizes, int n_in,
                              void* d_out, int out_size, void* d_ws, size_t ws_size,
                              hipStream_t stream) {
  (void)in_sizes; (void)n_in; (void)out_size;
  const float* x      = (const float*)d_in[0];
  const float* gamma  = (const float*)d_in[1];
  const float* beta   = (const float*)d_in[2];
  const float* conf_w = (const float*)d_in[3];
  const float* conf_b = (const float*)d_in[4];
  const float* rw     = (const float*)d_in[5];
  const float* rb     = (const float*)d_in[6];
  const float* w1     = (const float*)d_in[7];
  const float* b1     = (const float*)d_in[8];
  const float* w2     = (const float*)d_in[9];
  const float* b2     = (const float*)d_in[10];
  float* out = (float*)d_out;

  char* w = (char*)d_ws;
  auto alloc = [&](size_t bytes) { char* p = w; w += (bytes + 255) & ~255ULL; return p; };

  __hip_bfloat16* xn = (__hip_bfloat16*)alloc((size_t)N_TOK * DIM * 2);
  int*   lists  = (int*)alloc((size_t)NEXP * N_TOK * 4);
  float* wtsb   = (float*)alloc((size_t)NEXP * N_TOK * 4);
  int*   counts = (int*)alloc(NEXP * CSTR * 4);
  int*   bases  = (int*)alloc(256);
  int2*  idx    = (int2*)alloc((size_t)N_TOK * 8);
  size_t common = (size_t)(w - (char*)d_ws);

  const size_t hbufA = (size_t)(2 * N_TOK + 512) * HID * 2;
  const size_t wtA   = (size_t)NEXP * DIM * HID * 2;
  const size_t ybufN = (size_t)2 * N_TOK * DIM * 2;   // 33.5 MB, aliases w1t in planA
  const bool planA = ws_size >= common + hbufA + 2 * wtA + 4096;

  hipMemsetAsync(counts, 0, NEXP * CSTR * 4, stream);
  prep_kernel<<<N_TOK / 4, 256, 0, stream>>>(x, gamma, beta, conf_w, conf_b, rw, rb,
                                             xn, out, counts, lists, wtsb, idx);

  if (planA) {
    __hip_bfloat16* hbuf = (__hip_bfloat16*)alloc(hbufA);
    __hip_bfloat16* w1t  = (__hip_bfloat16*)alloc(wtA);
    __hip_bfloat16* w2t  = (__hip_bfloat16*)alloc(wtA);
    __hip_bfloat16* ybuf = w1t;  // w1t is dead after gemm1
    bases_kernel<<<1, 64, 0, stream>>>(counts, bases);
    transpose_cast64<<<dim3(HID / 64, DIM / 64, NEXP), 256, 0, stream>>>(w1, w1t, DIM, HID);
    transpose_cast64<<<dim3(DIM / 64, HID / 64, NEXP), 256, 0, stream>>>(w2, w2t, HID, DIM);
    gemm1_kernel<<<dim3(HID / 256, NEXP * 32), 512, 0, stream>>>(
        xn, w1t, b1, lists, counts, bases, hbuf, 0);
    gemm2_kernel<<<dim3(DIM / 256, NEXP * 32), 512, 0, stream>>>(
        hbuf, w2t, counts, bases, ybuf, 0);
    combine_kernel<<<N_TOK / 4, 256, 0, stream>>>(ybuf, b2, idx, wtsb, bases, out);
  } else {
    __hip_bfloat16* hbuf = (__hip_bfloat16*)alloc((size_t)(N_TOK + 512) * HID * 2);
    __hip_bfloat16* wt   = (__hip_bfloat16*)alloc((size_t)DIM * HID * 2);
    __hip_bfloat16* ybuf = (__hip_bfloat16*)alloc(ybufN);
    bases_kernel<<<1, 64, 0, stream>>>(counts, bases);
    for (int e = 0; e < NEXP; e++) {
      transpose_cast64<<<dim3(HID / 64, DIM / 64, 1), 256, 0, stream>>>(
          w1 + (size_t)e * DIM * HID, wt, DIM, HID);
      gemm1_kernel<<<dim3(HID / 256, 32), 512, 0, stream>>>(
          xn, wt, b1, lists, counts, bases, hbuf, e);
      transpose_cast64<<<dim3(DIM / 64, HID / 64, 1), 256, 0, stream>>>(
          w2 + (size_t)e * HID * DIM, wt, HID, DIM);
      gemm2_kernel<<<dim3(DIM / 256, 32), 512, 0, stream>>>(
          hbuf, wt, counts, bases, ybuf, e);
    }
    combine_kernel<<<N_TOK / 4, 256, 0, stream>>>(ybuf, b2, idx, wtsb, bases, out);
  }
}